// Round 9
// baseline (153.549 us; speedup 1.0000x reference)
//
#include <hip/hip_runtime.h>
#include <math.h>

#define NHEAD 8
#define BATCH 4
#define NN 1024              // H*W
#define MM 21
#define DD 84                // M*hd
#define DP 96                // padded feature dim
#define BN (BATCH*NHEAD)     // 32
#define NROWS (BATCH*NN*MM)  // 86016

typedef __attribute__((ext_vector_type(8))) short bf16x8;
typedef __attribute__((ext_vector_type(16))) float f32x16;

__device__ __forceinline__ unsigned short f2bf(float x) {
    union { float f; unsigned int u; } c; c.f = x;
    unsigned int r = (c.u + 0x7FFFu + ((c.u >> 16) & 1u)) >> 16;
    return (unsigned short)r;
}
__device__ __forceinline__ int qxmap(int r, int half) { return (r & 3) + 8*(r >> 2) + 4*half; }

// Fragment-linear layouts (ushort):
//  Qf/Kf: addr(bh,n,d) = ((bh*32 + n/32)*6 + d/16)*512 + ((d>>3)&1)*256 + (n&31)*8 + (d&7)
//  Vf:    addr(bh,n,d) = (bh*32 + n/32)*3072 + (d/32)*1024 + ((n>>4)&1)*512 + ((n>>3)&1)*256 + (d&31)*8 + (n&7)

// ================ L1: fused qkv-projection (blocks 0..671) + x2/Mg/pads (blocks 672..735) ================
__global__ __launch_bounds__(256)
void l1_kernel(const float* __restrict__ x, const float* __restrict__ Wq,
               const float* __restrict__ bq, const float* __restrict__ Wsq,
               const float* __restrict__ bsq, ushort* __restrict__ qf,
               ushort* __restrict__ kf, ushort* __restrict__ vb,
               float* __restrict__ x2, unsigned* __restrict__ Mg)
{
    int t = threadIdx.x;
    int w = t >> 6, lane = t & 63, col = lane & 31, half = lane >> 5;

    if (blockIdx.x < 672) {
        // ---------------- qkv role ----------------
        __shared__ ushort wqs[3072];
        __shared__ float bqs[96];
        __shared__ __align__(16) float xs[128*36];
        __shared__ ushort cs[4*3200];      // per-wave 32x(96+4) repack
        int R0 = blockIdx.x * 128;

        for (int i = t; i < 3072; i += 256) wqs[i] = f2bf(Wq[i]);
        if (t < 96) bqs[t] = bq[t];
        for (int i = t; i < 4096; i += 256)
            xs[(i >> 5)*36 + (i & 31)] = x[(size_t)R0*32 + i];
        __syncthreads();

        bf16x8 bw[3][2];
#pragma unroll
        for (int f = 0; f < 3; f++)
#pragma unroll
            for (int c = 0; c < 2; c++) {
                union { bf16x8 v; ushort s[8]; } u;
#pragma unroll
                for (int j = 0; j < 8; j++)
                    u.s[j] = wqs[(c*16 + half*8 + j)*96 + f*32 + col];
                bw[f][c] = u.v;
            }
        bf16x8 aw[2];
#pragma unroll
        for (int c = 0; c < 2; c++) {
            const float* xr = xs + (w*32 + col)*36 + c*16 + half*8;
            float4 v0 = *(const float4*)(xr);
            float4 v1 = *(const float4*)(xr + 4);
            union { bf16x8 v; ushort s[8]; } u;
            u.s[0]=f2bf(v0.x); u.s[1]=f2bf(v0.y); u.s[2]=f2bf(v0.z); u.s[3]=f2bf(v0.w);
            u.s[4]=f2bf(v1.x); u.s[5]=f2bf(v1.y); u.s[6]=f2bf(v1.z); u.s[7]=f2bf(v1.w);
            aw[c] = u.v;
        }
        f32x16 acc[3];
#pragma unroll
        for (int f = 0; f < 3; f++) {
#pragma unroll
            for (int r = 0; r < 16; r++) acc[f][r] = 0.f;
#pragma unroll
            for (int c = 0; c < 2; c++)
                acc[f] = __builtin_amdgcn_mfma_f32_32x32x16_bf16(aw[c], bw[f][c], acc[f], 0, 0, 0);
        }
        ushort* myc = cs + w*3200;
#pragma unroll
        for (int f = 0; f < 3; f++) {
            float sc = (f == 0) ? 0.03125f : 1.0f;   // fold qk scale into q
            float bb = bqs[f*32 + col];
#pragma unroll
            for (int r = 0; r < 16; r++)
                myc[qxmap(r, half)*100 + f*32 + col] = f2bf((acc[f][r] + bb)*sc);
        }
        __syncthreads();
        int row = lane >> 1, hr = lane & 1;
        int Rr = R0 + w*32 + row;
        int b_ = Rr / 21, m = Rr - b_*21, b = b_ >> 10, n = b_ & 1023;
        size_t fragoff = (size_t)(m >> 2)*512 + ((m >> 1) & 1)*256 + (n & 31)*8 + ((4*m) & 7);
        int nt = n >> 5;
#pragma unroll
        for (int c2 = 0; c2 < 12; c2++) {
            int col4 = hr*48 + c2*4;
            ushort4 v = *(const ushort4*)(myc + row*100 + col4);
            int s = col4 >> 5, hh = (col4 & 31) >> 2;
            if (s == 0)
                *(ushort4*)(qf + (size_t)((b*8 + hh)*32 + nt)*3072 + fragoff) = v;
            else if (s == 1)
                *(ushort4*)(kf + (size_t)((b*8 + hh)*32 + nt)*3072 + fragoff) = v;
            else
                *(ushort4*)(vb + ((size_t)((b*8 + hh)*1024 + n))*DD + m*4) = v;
        }
    } else {
        // ---------------- x2 role: 64 blocks, wave-per-row ----------------
        __shared__ __align__(16) float ws[84];
        int bx = blockIdx.x - 672;
        if (t < 84) ws[t] = Wsq[t];
        if (bx == 0 && t < 8) Mg[t] = 0u;
        __syncthreads();
        int wid = bx*4 + w;
        float bs0 = bsq[0];
        int dd = lane & 3;
        for (int rr = 0; rr < 16; rr++) {
            int rowi = wid*16 + rr;              // b*1024 + n
            int b = rowi >> 10, n = rowi & 1023;
            const float* xr = x + (size_t)rowi*672;
            float acc = 0.f;
#pragma unroll
            for (int p = 0; p < 11; p++) {
                int idx = p*64 + lane;
                int m = idx >> 5;
                if (m < 21) acc += xr[idx] * ws[m*4 + dd];
            }
            acc += __shfl_xor(acc, 32);
            acc += __shfl_xor(acc, 1);
            acc += __shfl_xor(acc, 2);
            if ((lane & 3) == 0 && lane < 32) {
                int h = lane >> 2;
                x2[(size_t)(b*8 + h)*1024 + n] = acc + bs0;
            }
            if (lane < 48) {
                int h = lane / 6, piece = lane % 6;
                size_t base = (size_t)((b*8 + h)*32 + (n >> 5))*3072 + 5*512 + (n & 31)*8;
                int pm = piece % 3;
                size_t off = (pm == 0) ? 4 : (pm == 1) ? 256 : 260;
                ushort* dst = (piece < 3) ? qf : kf;
                *(ushort4*)(dst + base + off) = make_ushort4(0,0,0,0);
            }
        }
    }
}

// ================ L2: fused vtr (blocks 0..511) + lspe-with-inline-pool (blocks 512..543) ================
__global__ __launch_bounds__(256)
void l2_kernel(const ushort* __restrict__ vb, ushort* __restrict__ vf,
               const float* __restrict__ x2, const float* __restrict__ Wdw,
               const float* __restrict__ bdw, float* __restrict__ xw,
               float* __restrict__ xp)
{
    int t = threadIdx.x;
    if (blockIdx.x < 512) {
        // ---------------- vtr role ----------------
        __shared__ ushort ld[64*88];
        int bh = blockIdx.x >> 4, n0 = (blockIdx.x & 15) * 64;
        for (int i = t; i < 1344; i += 256) {
            int r = i/21, p = i - r*21;
            *(ushort4*)(ld + r*88 + p*4) = *(const ushort4*)(vb + ((size_t)bh*NN + n0 + r)*DD + p*4);
        }
        __syncthreads();
        for (int j = t; j < 1344; j += 256) {
            int d = j >> 4, g = j & 15;
            ushort4 wv;
            wv.x = ld[(g*4+0)*88 + d]; wv.y = ld[(g*4+1)*88 + d];
            wv.z = ld[(g*4+2)*88 + d]; wv.w = ld[(g*4+3)*88 + d];
            int nn = n0 + g*4;
            size_t addr = (size_t)(bh*32 + (nn >> 5))*3072 + (d >> 5)*1024
                        + ((nn >> 4) & 1)*512 + ((nn >> 3) & 1)*256 + (d & 31)*8 + (nn & 7);
            *(ushort4*)(vf + addr) = wv;
        }
        if (t < 192) {
            int r = 84 + t/16, p = t & 15;
            int nn = n0 + p*4;
            ushort e = (r == 84) ? (ushort)0x3F80 : (ushort)0;
            size_t addr = (size_t)(bh*32 + (nn >> 5))*3072 + 2*1024
                        + ((nn >> 4) & 1)*512 + ((nn >> 3) & 1)*256 + (r & 31)*8 + (nn & 7);
            *(ushort4*)(vf + addr) = make_ushort4(e, e, e, e);
        }
    } else {
        // ---------------- lspe role with inline pool: 32 blocks ----------------
        __shared__ float sp[4];
        int idx = blockIdx.x - 512;
        int w = t >> 6, lane = t & 63;
        int i = idx*256 + t;
        int h = i >> 10;
        {
            const float* p = x2 + (size_t)(w*8 + h)*NN;
            float s = 0.f, mx = -INFINITY;
            for (int k = lane; k < NN; k += 64) { float v = p[k]; s += v; mx = fmaxf(mx, v); }
#pragma unroll
            for (int off = 1; off < 64; off <<= 1) {
                s  += __shfl_xor(s, off);
                mx  = fmaxf(mx, __shfl_xor(mx, off));
            }
            if (lane == 0) sp[w] = s * (1.f/1024.f) + mx;
        }
        __syncthreads();
        int n = i & 1023;
        int y = n >> 5, xx = n & 31;
        int g0 = h >> 1;
        float accW = 0.f, accP = 0.f;
        for (int b = 0; b < 4; b++) {
            float spl = sp[b];
            float c0 = bdw[h], c1 = bdw[8 + h];
            const float* a0 = x2 + (size_t)(b*8 + g0)*NN;
            const float* a1 = x2 + (size_t)(b*8 + 4 + g0)*NN;
#pragma unroll
            for (int ky = 0; ky < 3; ky++) {
                int yy = y + ky - 1;
                if (yy < 0 || yy > 31) continue;
#pragma unroll
                for (int kx = 0; kx < 3; kx++) {
                    int xc = xx + kx - 1;
                    if (xc < 0 || xc > 31) continue;
                    c0 += a0[yy*32 + xc] * Wdw[h*9 + ky*3 + kx];
                    c1 += a1[yy*32 + xc] * Wdw[(8+h)*9 + ky*3 + kx];
                }
            }
            accW += c0 + spl;
            accP += c1 + spl;
        }
        xw[i] = 0.25f * accW;
        xp[i] = 0.25f * accP;
    }
}

// ================ L3: correlation -> 63x63 bias table + per-head global max ================
__global__ __launch_bounds__(512)
void bias_kernel(const float* __restrict__ xw, const float* __restrict__ xp,
                 float* __restrict__ btab, unsigned* __restrict__ Mg)
{
    __shared__ float sxw[1024], sxp[1024];
    __shared__ float part[8][64];
    int h = blockIdx.y, oy = blockIdx.x;
    int t = threadIdx.x;
    for (int i = t; i < 1024; i += 512) { sxw[i] = xw[h*1024+i]; sxp[i] = xp[h*1024+i]; }
    __syncthreads();
    int ox = t & 63;
    int aw = t >> 6;
    int alo = max(0, oy-31), ahi = min(31, oy);
    int clo = max(0, ox-31), chi = min(31, ox);
    int cnt = chi - clo + 1;
    float acc0 = 0.f, acc1 = 0.f;
    if (ox < 63) {
        for (int a = alo + aw; a <= ahi; a += 8) {
            const float* prow = sxp + a*32 + clo;
            const float* wrow = sxw + (oy - a)*32 + (ox - clo);
            int k = 0;
            for (; k + 1 < cnt; k += 2) {
                acc0 += prow[k]   * wrow[-k];
                acc1 += prow[k+1] * wrow[-k-1];
            }
            if (k < cnt) acc0 += prow[k] * wrow[-k];
        }
    }
    part[aw][ox] = acc0 + acc1;
    __syncthreads();
    if (t < 64) {
        float acc = 0.f;
#pragma unroll
        for (int j = 0; j < 8; j++) acc += part[j][t];
        unsigned key = 0u;
        if (t < 63) {
            btab[h*3969 + oy*63 + t] = acc;
            unsigned u = __float_as_uint(acc);
            key = (u & 0x80000000u) ? ~u : (u | 0x80000000u);
        }
#pragma unroll
        for (int off = 1; off < 64; off <<= 1) {
            unsigned o = __shfl_xor(key, off);
            key = key > o ? key : o;
        }
        if (t == 0) atomicMax(Mg + h, key);
    }
}

// ================ L4: barrier-free MFMA flash attention, multiplicative exp-bias ================
// grid 1024: bh = bid&31 (XCD-local), qt = bid>>5; 4 independent waves, wave w owns kt = 4j+w.
__global__ __launch_bounds__(256, 4)
void attn_kernel(const ushort* __restrict__ qg, const ushort* __restrict__ kg,
                 const ushort* __restrict__ vg, const float* __restrict__ btg,
                 const unsigned* __restrict__ Mg, float* __restrict__ Obuf)
{
    __shared__ float btabS[2016];        // exp(bias - M) for the 32 reachable table rows
    __shared__ float red[2][64*52];
    __shared__ float lred[32];

    int t = threadIdx.x;
    int bid = blockIdx.x;
    int bh = bid & 31, qt = bid >> 5;
    int h = bh & 7, b = bh >> 3;
    int q0 = qt * 32;

    float Mh;
    { unsigned k = Mg[h]; unsigned u = (k & 0x80000000u) ? (k ^ 0x80000000u) : ~k; Mh = __uint_as_float(u); }
    const float* bsrc = btg + h*3969 + qt*63;      // rows yq .. yq+31
    for (int i = t; i < 2016; i += 256) btabS[i] = __expf(bsrc[i] - Mh);
    __syncthreads();

    int w = t >> 6, lane = t & 63, col = lane & 31, half = lane >> 5;
    int lofs = half*256 + col*8;

    bf16x8 bq6[6];
    const ushort* qbase = qg + (size_t)(bh*32 + qt)*3072 + lofs;
#pragma unroll
    for (int s = 0; s < 6; s++) bq6[s] = *(const bf16x8*)(qbase + s*512);

    f32x16 of[3];
#pragma unroll
    for (int f = 0; f < 3; f++)
#pragma unroll
        for (int r = 0; r < 16; r++) of[f][r] = 0.f;

    int kx_[16];
#pragma unroll
    for (int r = 0; r < 16; r++) kx_[r] = qxmap(r, half);

    const ushort* kall = kg + (size_t)bh*32*3072 + lofs;
    const ushort* vall = vg + (size_t)bh*32*3072 + lofs;

    bf16x8 akc[6];
    {
        const ushort* kr = kall + (size_t)w*3072;
#pragma unroll
        for (int s = 0; s < 6; s++) akc[s] = *(const bf16x8*)(kr + s*512);
    }

    for (int j = 0; j < 8; j++) {
        int kt = 4*j + w;
        // V B-frags — issued early, consumed after softmax
        const ushort* vr = vall + (size_t)kt*3072;
        bf16x8 vfr[3][2];
#pragma unroll
        for (int f = 0; f < 3; f++)
#pragma unroll
            for (int c = 0; c < 2; c++)
                vfr[f][c] = *(const bf16x8*)(vr + f*1024 + c*512);

        // ebias loads — independent of the MFMA chain, overlap with QK
        const float* bp = btabS + (31 - kt)*63 + col + 31;
        float eb[16];
#pragma unroll
        for (int g = 0; g < 16; g++) eb[g] = bp[-kx_[g]];

        // St = K.Q^T : D[m=key][n=q]
        f32x16 st;
#pragma unroll
        for (int r = 0; r < 16; r++) st[r] = 0.f;
#pragma unroll
        for (int s = 0; s < 6; s++)
            st = __builtin_amdgcn_mfma_f32_32x32x16_bf16(akc[s], bq6[s], st, 0, 0, 0);

        // prefetch next K tile
        bf16x8 akn[6];
        if (j < 7) {
            const ushort* kr = kall + (size_t)(kt + 4)*3072;
#pragma unroll
            for (int s = 0; s < 6; s++) akn[s] = *(const bf16x8*)(kr + s*512);
        }

        // P = expf(st) * ebias, packed to bf16 pairs (round-half-up)
        unsigned P[8];
#pragma unroll
        for (int g = 0; g < 8; g++) {
            float p0 = __expf(st[2*g])   * eb[2*g];
            float p1 = __expf(st[2*g+1]) * eb[2*g+1];
            unsigned u0 = __float_as_uint(p0) + 0x8000u;
            unsigned u1 = __float_as_uint(p1) + 0x8000u;
            P[g] = (u1 & 0xFFFF0000u) | (u0 >> 16);
        }
        unsigned XP[8];
#pragma unroll
        for (int g = 0; g < 8; g++) XP[g] = (unsigned)__shfl_xor((int)P[g], 32);

        union { bf16x8 v; unsigned u[4]; } f0, f1;
        f0.u[0] = half ? XP[2] : P[0];
        f0.u[1] = half ? XP[3] : P[1];
        f0.u[2] = half ? P[2]  : XP[0];
        f0.u[3] = half ? P[3]  : XP[1];
        f1.u[0] = half ? XP[6] : P[4];
        f1.u[1] = half ? XP[7] : P[5];
        f1.u[2] = half ? P[6]  : XP[4];
        f1.u[3] = half ? P[7]  : XP[5];

        // O += P.V ; l accumulates via ones-row d=84
#pragma unroll
        for (int f = 0; f < 3; f++) {
            of[f] = __builtin_amdgcn_mfma_f32_32x32x16_bf16(f0.v, vfr[f][0], of[f], 0, 0, 0);
            of[f] = __builtin_amdgcn_mfma_f32_32x32x16_bf16(f1.v, vfr[f][1], of[f], 0, 0, 0);
        }
        if (j < 7) {
#pragma unroll
            for (int s = 0; s < 6; s++) akc[s] = akn[s];
        }
    }

    // ---- 4-way O reduction (tree) + epilogue ----
    __syncthreads();
    if (w == 1 || w == 3) {
        float* dst = red[w >> 1] + lane*52;
#pragma unroll
        for (int f = 0; f < 3; f++)
#pragma unroll
            for (int r = 0; r < 16; r++) dst[f*16 + r] = of[f][r];
    }
    __syncthreads();
    if (w == 0 || w == 2) {
        const float* src = red[w >> 1] + lane*52;
#pragma unroll
        for (int f = 0; f < 3; f++)
#pragma unroll
            for (int r = 0; r < 16; r++) of[f][r] += src[f*16 + r];
    }
    __syncthreads();
    if (w == 2) {
        float* dst = red[0] + lane*52;
#pragma unroll
        for (int f = 0; f < 3; f++)
#pragma unroll
            for (int r = 0; r < 16; r++) dst[f*16 + r] = of[f][r];
    }
    __syncthreads();
    if (w == 0) {
        const float* src = red[0] + lane*52;
#pragma unroll
        for (int f = 0; f < 3; f++)
#pragma unroll
            for (int r = 0; r < 16; r++) of[f][r] += src[f*16 + r];
        if (col == 20) {
#pragma unroll
            for (int r = 0; r < 16; r++) lred[qxmap(r, half)] = of[2][r];
        }
    }
    __syncthreads();
    if (w == 0) {
        float linv[16];
#pragma unroll
        for (int r = 0; r < 16; r++) linv[r] = 1.0f / lred[qxmap(r, half)];
#pragma unroll
        for (int f = 0; f < 3; f++) {
            int d = f*32 + col;
            if (d < DD) {
                int m = d >> 2, dd2 = d & 3;
#pragma unroll
                for (int r = 0; r < 16; r++) {
                    int q = qxmap(r, half);
                    size_t R = ((size_t)(b*NN + q0 + q))*21 + m;
                    Obuf[R*32 + h*4 + dd2] = of[f][r] * linv[r];
                }
            }
        }
    }
}

// ================ L5: output projection via MFMA (LDS-staged activations) ================
__global__ __launch_bounds__(256)
void proj_kernel(const float* __restrict__ Obuf, const float* __restrict__ Wp,
                 const float* __restrict__ bp, float* __restrict__ out)
{
    __shared__ ushort wps[1024];
    __shared__ float bps[32];
    __shared__ __align__(16) float os[128*36];
    int t = threadIdx.x;
    int w = t >> 6, lane = t & 63, col = lane & 31, half = lane >> 5;
    int R0 = blockIdx.x * 128;
    for (int i = t; i < 1024; i += 256) wps[i] = f2bf(Wp[i]);
    if (t < 32) bps[t] = bp[t];
    for (int i = t; i < 4096; i += 256)
        os[(i >> 5)*36 + (i & 31)] = Obuf[(size_t)R0*32 + i];
    __syncthreads();

    bf16x8 bw[2];
#pragma unroll
    for (int c = 0; c < 2; c++) {
        union { bf16x8 v; ushort s[8]; } u;
#pragma unroll
        for (int j = 0; j < 8; j++)
            u.s[j] = wps[(c*16 + half*8 + j)*32 + col];
        bw[c] = u.v;
    }
    bf16x8 aw[2];
#pragma unroll
    for (int c = 0; c < 2; c++) {
        const float* orr = os + (w*32 + col)*36 + c*16 + half*8;
        float4 v0 = *(const float4*)(orr);
        float4 v1 = *(const float4*)(orr + 4);
        union { bf16x8 v; ushort s[8]; } u;
        u.s[0]=f2bf(v0.x); u.s[1]=f2bf(v0.y); u.s[2]=f2bf(v0.z); u.s[3]=f2bf(v0.w);
        u.s[4]=f2bf(v1.x); u.s[5]=f2bf(v1.y); u.s[6]=f2bf(v1.z); u.s[7]=f2bf(v1.w);
        aw[c] = u.v;
    }
    f32x16 acc;
#pragma unroll
    for (int r = 0; r < 16; r++) acc[r] = 0.f;
#pragma unroll
    for (int c = 0; c < 2; c++)
        acc = __builtin_amdgcn_mfma_f32_32x32x16_bf16(aw[c], bw[c], acc, 0, 0, 0);
    float bb = bps[col];
#pragma unroll
    for (int r = 0; r < 16; r++)
        out[(size_t)(R0 + w*32 + qxmap(r, half))*32 + col] = acc[r] + bb;
}

extern "C" void kernel_launch(void* const* d_in, const int* in_sizes, int n_in,
                              void* d_out, int out_size, void* d_ws, size_t ws_size,
                              hipStream_t stream)
{
    const float* x     = (const float*)d_in[0];
    const float* Wqkv  = (const float*)d_in[1];
    const float* bqkv  = (const float*)d_in[2];
    const float* Wproj = (const float*)d_in[3];
    const float* bproj = (const float*)d_in[4];
    const float* Wsq   = (const float*)d_in[5];
    const float* bsq   = (const float*)d_in[6];
    const float* Wdw   = (const float*)d_in[7];
    const float* bdw   = (const float*)d_in[8];

    const size_t QP = (size_t)BN * NN * DP;   // 3,145,728
    const size_t VB = (size_t)BN * NN * DD;   // 2,752,512
    ushort* qf   = (ushort*)d_ws;
    ushort* kf   = qf + QP;
    ushort* vb   = kf + QP;
    ushort* vf   = vb + VB;
    float* Obuf  = (float*)(vf + QP);
    float* x2    = Obuf + VB;
    float* xw    = x2 + 32768;
    float* xp    = xw + 8192;
    float* btab  = xp + 8192;
    unsigned* Mg = (unsigned*)(btab + 3969*8);
    float* out   = (float*)d_out;

    l1_kernel  <<<736,        256, 0, stream>>>(x, Wqkv, bqkv, Wsq, bsq, qf, kf, vb, x2, Mg);
    l2_kernel  <<<544,        256, 0, stream>>>(vb, vf, x2, Wdw, bdw, xw, xp);
    bias_kernel<<<dim3(63,8), 512, 0, stream>>>(xw, xp, btab, Mg);
    attn_kernel<<<1024,       256, 0, stream>>>(qf, kf, vf, btab, Mg, Obuf);
    proj_kernel<<<NROWS/128,  256, 0, stream>>>(Obuf, Wproj, bproj, out);
}